// Round 6
// baseline (720.196 us; speedup 1.0000x reference)
//
#include <hip/hip_runtime.h>
#include <math.h>

#define B 2
#define N 512
#define DIM 256
#define HEADS 8
#define DHEAD 32
#define INNER 256
#define DEPTH 2
#define SCALE 0.17677669529663687f
#define NB 512u

// ---- device-scope sense-reversing grid barrier (all NB blocks co-resident) ----
__device__ __forceinline__ void gbar(unsigned* cnt, unsigned* gen) {
    __syncthreads();
    if (threadIdx.x == 0) {
        __threadfence();   // prior global writes visible device-wide
        unsigned g = __hip_atomic_load(gen, __ATOMIC_RELAXED, __HIP_MEMORY_SCOPE_AGENT);
        unsigned old = __hip_atomic_fetch_add(cnt, 1u, __ATOMIC_ACQ_REL, __HIP_MEMORY_SCOPE_AGENT);
        if (old == NB - 1u) {
            __hip_atomic_store(cnt, 0u, __ATOMIC_RELAXED, __HIP_MEMORY_SCOPE_AGENT);
            __hip_atomic_fetch_add(gen, 1u, __ATOMIC_ACQ_REL, __HIP_MEMORY_SCOPE_AGENT);
        } else {
            while (__hip_atomic_load(gen, __ATOMIC_ACQUIRE, __HIP_MEMORY_SCOPE_AGENT) == g)
                __builtin_amdgcn_s_sleep(1);
        }
    }
    __syncthreads();
}

// ---- block-wide sum over 256 threads, broadcast ----
__device__ __forceinline__ float block_sum256(float v, float* red4) {
    #pragma unroll
    for (int o = 32; o; o >>= 1) v += __shfl_xor(v, o);
    int tid = threadIdx.x;
    __syncthreads();
    if ((tid & 63) == 0) red4[tid >> 6] = v;
    __syncthreads();
    return red4[0] + red4[1] + red4[2] + red4[3];
}

// ---- per-row sum over 128 threads (rows = 2 waves each), broadcast ----
__device__ __forceinline__ float rowsum128(float v, float* red, int ty) {
    #pragma unroll
    for (int o = 32; o; o >>= 1) v += __shfl_xor(v, o);
    __syncthreads();
    if ((threadIdx.x & 63) == 0) red[threadIdx.x >> 6] = v;
    __syncthreads();
    return red[ty*2] + red[ty*2 + 1];
}

__global__ __launch_bounds__(256, 2)
void k_fused(const float* __restrict__ x, const float* __restrict__ t,
             const float* __restrict__ Wenc, const float* __restrict__ Wdec,
             const float* __restrict__ ln_g, const float* __restrict__ ln_b,
             const float* __restrict__ Wq, const float* __restrict__ bq,
             const float* __restrict__ Wkv, const float* __restrict__ bkv,
             const float* __restrict__ We, const float* __restrict__ be,
             const float* __restrict__ Wo, const float* __restrict__ bo,
             const float* __restrict__ Wg,
             float* __restrict__ nodes, float* __restrict__ dist, float* __restrict__ hbuf,
             float* __restrict__ qbuf, float* __restrict__ kbuf, float* __restrict__ vbuf,
             float* __restrict__ qwe, float* __restrict__ qbe, float* __restrict__ attnout,
             float* __restrict__ ct, float* __restrict__ st, float* __restrict__ out,
             unsigned* bcnt, unsigned* bgen)
{
    __shared__ float smem[6144];           // 24 KB, re-carved per phase
    int tid = threadIdx.x;
    int blk = blockIdx.x;

    // ================= PHASE PRE: tables + encode + LN0 + dist =================
    {
        if (blk < 32) {                    // rotary tables (8192 entries)
            int idx = blk*256 + tid;
            int ii = idx >> 4, jj = idx & 15;
            double invf = pow(10000.0, -(double)jj / 16.0);
            double ang = (double)ii * invf;
            ct[idx] = (float)cos(ang);
            st[idx] = (float)sin(ang);
        }
        float* red4 = smem;                // [4]
        float* xs   = smem + 16;           // [1536]
        for (int it = 0; it < 2; ++it) {
            int row = blk + it*NB;         // 0..1023
            int b = row >> 9, i = row & (N-1);
            float x0 = x[row*3+0], x1 = x[row*3+1], x2 = x[row*3+2], tt = t[row];
            int d = tid;
            float nv = x0*Wenc[d] + x1*Wenc[DIM+d] + x2*Wenc[2*DIM+d] + tt*Wenc[3*DIM+d];
            nodes[row*DIM + d] = nv;
            float mean = block_sum256(nv, red4) * (1.0f/DIM);
            float c = nv - mean;
            float var = block_sum256(c*c, red4) * (1.0f/DIM);
            hbuf[row*DIM + d] = c * (1.0f/sqrtf(var + 1e-5f)) * ln_g[d] + ln_b[d];

            __syncthreads();
            for (int f = tid; f < N*3; f += 256) xs[f] = x[b*N*3 + f];
            __syncthreads();
            float xi0 = xs[i*3+0], xi1 = xs[i*3+1], xi2 = xs[i*3+2];
            for (int j = tid; j < N; j += 256) {
                float d0 = xi0 - xs[j*3+0], d1 = xi1 - xs[j*3+1], d2 = xi2 - xs[j*3+2];
                float s = d0*d0 + d1*d1 + d2*d2;
                dist[(size_t)row*N + j] = (s > 0.f) ? sqrtf(s) : 0.f;
            }
            __syncthreads();               // xs/red4 reused next iter
        }
    }
    gbar(bcnt, bgen);

    for (int l = 0; l < DEPTH; ++l) {
        // ================= PHASE QKV GEMM + rotary + qwe/qbe =================
        if (blk < 384) {
            float* AT = smem;              // [64][32]
            float* Bs = smem + 2048;       // [64][64]
            int mt = blk & 31;
            int nt = blk >> 5;
            int tx = tid & 15, ty = tid >> 4;
            int n0 = nt * 64;

            const float* Wsrc; int wstride;
            if (n0 < 256) { Wsrc = Wq  + (size_t)l*256*256 + n0;        wstride = 256; }
            else          { Wsrc = Wkv + (size_t)l*256*512 + (n0-256);  wstride = 512; }

            float acc[2][4] = {{0,0,0,0},{0,0,0,0}};
            int am = tid & 31, ak = tid >> 5;
            int bn4 = tid & 15, bk = tid >> 4;

            for (int kt = 0; kt < 4; ++kt) {
                int kbase = kt * 64;
                if (kt) __syncthreads();
                {
                    const float* src = hbuf + (size_t)(mt*32 + am)*256 + kbase + ak*8;
                    float4 a0 = *(const float4*)src;
                    float4 a1 = *(const float4*)(src + 4);
                    AT[(ak*8+0)*32+am]=a0.x; AT[(ak*8+1)*32+am]=a0.y;
                    AT[(ak*8+2)*32+am]=a0.z; AT[(ak*8+3)*32+am]=a0.w;
                    AT[(ak*8+4)*32+am]=a1.x; AT[(ak*8+5)*32+am]=a1.y;
                    AT[(ak*8+6)*32+am]=a1.z; AT[(ak*8+7)*32+am]=a1.w;
                }
                #pragma unroll
                for (int p = 0; p < 4; ++p) {
                    int k = bk + p*16;
                    float4 v = *(const float4*)(Wsrc + (size_t)(kbase + k)*wstride + bn4*4);
                    *(float4*)&Bs[k*64 + bn4*4] = v;
                }
                __syncthreads();
                #pragma unroll 8
                for (int k = 0; k < 64; ++k) {
                    float2 a = *(const float2*)&AT[k*32 + ty*2];
                    float4 b = *(const float4*)&Bs[k*64 + tx*4];
                    acc[0][0] += a.x*b.x; acc[0][1] += a.x*b.y; acc[0][2] += a.x*b.z; acc[0][3] += a.x*b.w;
                    acc[1][0] += a.y*b.x; acc[1][1] += a.y*b.y; acc[1][2] += a.y*b.z; acc[1][3] += a.y*b.w;
                }
            }

            int row = mt*32 + ty*2;
            int n = n0 + tx*4;
            float4 bias4;
            if (n0 < 256) bias4 = *(const float4*)&bq[l*256 + n];
            else          bias4 = *(const float4*)&bkv[l*512 + (n - 256)];
            #pragma unroll
            for (int r = 0; r < 2; ++r) {
                acc[r][0] += bias4.x; acc[r][1] += bias4.y; acc[r][2] += bias4.z; acc[r][3] += bias4.w;
            }

            if (n0 >= 512) {               // V tile
                #pragma unroll
                for (int r = 0; r < 2; ++r) {
                    float4 o = make_float4(acc[r][0], acc[r][1], acc[r][2], acc[r][3]);
                    *(float4*)&vbuf[(size_t)(row + r)*256 + (n - 512)] = o;
                }
            } else {
                // rotary partner exchange via Bs scratch (stride 68)
                float* sh = Bs;
                __syncthreads();
                #pragma unroll
                for (int r = 0; r < 2; ++r)
                    #pragma unroll
                    for (int c = 0; c < 4; ++c)
                        sh[(ty*2 + r)*68 + tx*4 + c] = acc[r][c];
                __syncthreads();

                float wep[2] = {0.f, 0.f}, bep[2] = {0.f, 0.f};
                float val[2][4];
                #pragma unroll
                for (int r = 0; r < 2; ++r) {
                    int ii = (row + r) & (N-1);
                    #pragma unroll
                    for (int c = 0; c < 4; ++c) {
                        int tc = tx*4 + c;
                        int dd = tc & 31, jj = tc & 15;
                        float ca = ct[ii*16 + jj], sa = st[ii*16 + jj];
                        int ptc = (dd < 16) ? tc + 16 : tc - 16;
                        float sgn = (dd < 16) ? -1.f : 1.f;
                        float partner = sh[(ty*2 + r)*68 + ptc];
                        float rot = acc[r][c]*ca + sgn*partner*sa;
                        val[r][c] = rot;
                        if (n0 < 256) {
                            wep[r] += rot * We[l*256 + n0 + tc];
                            bep[r] += rot * be[l*256 + n0 + tc];
                        }
                    }
                }
                float* dst = (n0 < 256) ? qbuf : kbuf;
                int coln = (n0 < 256) ? n : n - 256;
                #pragma unroll
                for (int r = 0; r < 2; ++r) {
                    float4 o = make_float4(val[r][0], val[r][1], val[r][2], val[r][3]);
                    *(float4*)&dst[(size_t)(row + r)*256 + coln] = o;
                }
                if (n0 < 256) {
                    #pragma unroll
                    for (int r = 0; r < 2; ++r) {
                        wep[r] += __shfl_xor(wep[r], 1); bep[r] += __shfl_xor(bep[r], 1);
                        wep[r] += __shfl_xor(wep[r], 2); bep[r] += __shfl_xor(bep[r], 2);
                        wep[r] += __shfl_xor(wep[r], 4); bep[r] += __shfl_xor(bep[r], 4);
                    }
                    if ((tid & 7) == 0) {
                        int h = nt*2 + (tx >> 3);
                        int bb = row >> 9;
                        #pragma unroll
                        for (int r = 0; r < 2; ++r) {
                            int ii = (row + r) & (N-1);
                            qwe[(bb*HEADS + h)*N + ii] = wep[r];
                            qbe[(bb*HEADS + h)*N + ii] = bep[r];
                        }
                    }
                }
            }
        }
        gbar(bcnt, bgen);

        // ================= PHASE ATTN (TI=16, 2 rows/thread) =================
        {
            float* Tt = smem;              // [32][128]
            int g = tid & 31;
            int r = tid >> 5;
            int itile = blk & 31;
            int h = (blk >> 5) & (HEADS-1);
            int b = blk >> 8;
            int i0 = itile*16 + r;
            int i1 = i0 + 8;
            int scol = tid & 127;
            int d0   = (tid >> 7) * 16;

            float q0[32], q1[32];
            {
                const float4* qp0 = (const float4*)(qbuf + (size_t)(b*N + i0)*INNER + h*DHEAD);
                const float4* qp1 = (const float4*)(qbuf + (size_t)(b*N + i1)*INNER + h*DHEAD);
                #pragma unroll
                for (int c = 0; c < 8; ++c) {
                    float4 v0 = qp0[c], v1 = qp1[c];
                    q0[c*4+0]=v0.x; q0[c*4+1]=v0.y; q0[c*4+2]=v0.z; q0[c*4+3]=v0.w;
                    q1[c*4+0]=v1.x; q1[c*4+1]=v1.y; q1[c*4+2]=v1.z; q1[c*4+3]=v1.w;
                }
            }
            float qw0 = qwe[(b*HEADS + h)*N + i0], qb0 = qbe[(b*HEADS + h)*N + i0];
            float qw1 = qwe[(b*HEADS + h)*N + i1], qb1 = qbe[(b*HEADS + h)*N + i1];

            const float* kbase = kbuf + (size_t)b*N*INNER + h*DHEAD;
            const float* vbase = vbuf + (size_t)b*N*INNER + h*DHEAD;
            const float* drow0 = dist + (size_t)(b*N + i0) * N;
            const float* drow1 = dist + (size_t)(b*N + i1) * N;

            float sim0[16], sim1[16];

            #pragma unroll
            for (int jt = 0; jt < 4; ++jt) {
                __syncthreads();
                {
                    const float* src = kbase + (size_t)(jt*128 + scol)*INNER + d0;
                    float4 a0 = *(const float4*)(src + 0);
                    float4 a1 = *(const float4*)(src + 4);
                    float4 a2 = *(const float4*)(src + 8);
                    float4 a3 = *(const float4*)(src + 12);
                    Tt[(d0+ 0)*128+scol]=a0.x; Tt[(d0+ 1)*128+scol]=a0.y;
                    Tt[(d0+ 2)*128+scol]=a0.z; Tt[(d0+ 3)*128+scol]=a0.w;
                    Tt[(d0+ 4)*128+scol]=a1.x; Tt[(d0+ 5)*128+scol]=a1.y;
                    Tt[(d0+ 6)*128+scol]=a1.z; Tt[(d0+ 7)*128+scol]=a1.w;
                    Tt[(d0+ 8)*128+scol]=a2.x; Tt[(d0+ 9)*128+scol]=a2.y;
                    Tt[(d0+10)*128+scol]=a2.z; Tt[(d0+11)*128+scol]=a2.w;
                    Tt[(d0+12)*128+scol]=a3.x; Tt[(d0+13)*128+scol]=a3.y;
                    Tt[(d0+14)*128+scol]=a3.z; Tt[(d0+15)*128+scol]=a3.w;
                }
                __syncthreads();
                float4 s0 = make_float4(0.f,0.f,0.f,0.f);
                float4 s1 = make_float4(0.f,0.f,0.f,0.f);
                #pragma unroll
                for (int d = 0; d < 32; ++d) {
                    float4 kv = *(const float4*)&Tt[d*128 + g*4];
                    float qa = q0[d], qc = q1[d];
                    s0.x += qa*kv.x; s0.y += qa*kv.y; s0.z += qa*kv.z; s0.w += qa*kv.w;
                    s1.x += qc*kv.x; s1.y += qc*kv.y; s1.z += qc*kv.z; s1.w += qc*kv.w;
                }
                float4 dv0 = *(const float4*)&drow0[jt*128 + g*4];
                float4 dv1 = *(const float4*)&drow1[jt*128 + g*4];
                sim0[jt*4+0]=(s0.x+dv0.x*qw0+qb0)*SCALE; sim0[jt*4+1]=(s0.y+dv0.y*qw0+qb0)*SCALE;
                sim0[jt*4+2]=(s0.z+dv0.z*qw0+qb0)*SCALE; sim0[jt*4+3]=(s0.w+dv0.w*qw0+qb0)*SCALE;
                sim1[jt*4+0]=(s1.x+dv1.x*qw1+qb1)*SCALE; sim1[jt*4+1]=(s1.y+dv1.y*qw1+qb1)*SCALE;
                sim1[jt*4+2]=(s1.z+dv1.z*qw1+qb1)*SCALE; sim1[jt*4+3]=(s1.w+dv1.w*qw1+qb1)*SCALE;
            }

            float mx0 = -1e30f, mx1 = -1e30f;
            #pragma unroll
            for (int v = 0; v < 16; ++v) { mx0 = fmaxf(mx0, sim0[v]); mx1 = fmaxf(mx1, sim1[v]); }
            #pragma unroll
            for (int o = 1; o <= 16; o <<= 1) {
                mx0 = fmaxf(mx0, __shfl_xor(mx0, o));
                mx1 = fmaxf(mx1, __shfl_xor(mx1, o));
            }

            float ls0 = 0.f, ld0 = 0.f, ls1 = 0.f, ld1 = 0.f;
            #pragma unroll
            for (int jt = 0; jt < 4; ++jt) {
                float4 dv0 = *(const float4*)&drow0[jt*128 + g*4];
                float4 dv1 = *(const float4*)&drow1[jt*128 + g*4];
                float a0[4] = {dv0.x,dv0.y,dv0.z,dv0.w};
                float a1[4] = {dv1.x,dv1.y,dv1.z,dv1.w};
                #pragma unroll
                for (int u = 0; u < 4; ++u) {
                    float p0 = __expf(sim0[jt*4+u] - mx0);
                    float p1 = __expf(sim1[jt*4+u] - mx1);
                    sim0[jt*4+u] = p0; sim1[jt*4+u] = p1;
                    ls0 += p0; ld0 += p0*a0[u];
                    ls1 += p1; ld1 += p1*a1[u];
                }
            }
            #pragma unroll
            for (int o = 1; o <= 16; o <<= 1) {
                ls0 += __shfl_xor(ls0, o); ld0 += __shfl_xor(ld0, o);
                ls1 += __shfl_xor(ls1, o); ld1 += __shfl_xor(ld1, o);
            }

            float acc0[32], acc1[32];
            #pragma unroll
            for (int d = 0; d < 32; ++d) { acc0[d] = 0.f; acc1[d] = 0.f; }

            #pragma unroll
            for (int jt = 0; jt < 4; ++jt) {
                __syncthreads();
                {
                    const float* src = vbase + (size_t)(jt*128 + scol)*INNER + d0;
                    float4 a0 = *(const float4*)(src + 0);
                    float4 a1 = *(const float4*)(src + 4);
                    float4 a2 = *(const float4*)(src + 8);
                    float4 a3 = *(const float4*)(src + 12);
                    Tt[(d0+ 0)*128+scol]=a0.x; Tt[(d0+ 1)*128+scol]=a0.y;
                    Tt[(d0+ 2)*128+scol]=a0.z; Tt[(d0+ 3)*128+scol]=a0.w;
                    Tt[(d0+ 4)*128+scol]=a1.x; Tt[(d0+ 5)*128+scol]=a1.y;
                    Tt[(d0+ 6)*128+scol]=a1.z; Tt[(d0+ 7)*128+scol]=a1.w;
                    Tt[(d0+ 8)*128+scol]=a2.x; Tt[(d0+ 9)*128+scol]=a2.y;
                    Tt[(d0+10)*128+scol]=a2.z; Tt[(d0+11)*128+scol]=a2.w;
                    Tt[(d0+12)*128+scol]=a3.x; Tt[(d0+13)*128+scol]=a3.y;
                    Tt[(d0+14)*128+scol]=a3.z; Tt[(d0+15)*128+scol]=a3.w;
                }
                __syncthreads();
                float p00=sim0[jt*4+0], p01=sim0[jt*4+1], p02=sim0[jt*4+2], p03=sim0[jt*4+3];
                float p10=sim1[jt*4+0], p11=sim1[jt*4+1], p12=sim1[jt*4+2], p13=sim1[jt*4+3];
                #pragma unroll
                for (int d = 0; d < 32; ++d) {
                    float4 vv = *(const float4*)&Tt[d*128 + g*4];
                    acc0[d] += p00*vv.x + p01*vv.y + p02*vv.z + p03*vv.w;
                    acc1[d] += p10*vv.x + p11*vv.y + p12*vv.z + p13*vv.w;
                }
            }

            #pragma unroll
            for (int d = 0; d < 32; ++d) {
                #pragma unroll
                for (int o = 1; o <= 16; o <<= 1) {
                    acc0[d] += __shfl_xor(acc0[d], o);
                    acc1[d] += __shfl_xor(acc1[d], o);
                }
            }

            float il0 = 1.0f/ls0, il1 = 1.0f/ls1;
            float ad0 = ld0*il0, ad1 = ld1*il1;
            float o0 = acc0[0], o1 = acc1[0];
            #pragma unroll
            for (int d = 1; d < 32; ++d) if (g == d) { o0 = acc0[d]; o1 = acc1[d]; }
            float wv = We[l*INNER + h*DHEAD + g];
            float bv = be[l*INNER + h*DHEAD + g];
            attnout[(size_t)(b*N + i0)*INNER + h*DHEAD + g] = o0*il0 + ad0*wv + bv;
            attnout[(size_t)(b*N + i1)*INNER + h*DHEAD + g] = o1*il1 + ad1*wv + bv;
        }
        gbar(bcnt, bgen);

        // ========== PHASE O-GEMM (BM=2, full row) + gate + LN/decode ==========
        {
            float* arow = smem;            // [512]
            float* red  = smem + 512;      // [4]
            int ty = tid >> 7;             // row within block
            int tx = tid & 127;
            int rg = blk*2 + ty;           // global row 0..1023
            int c0 = tx*2, c1 = c0 + 1;

            *(float2*)&arow[tid*2] = *(const float2*)&attnout[(size_t)blk*512 + tid*2];
            __syncthreads();

            const float* Wol = Wo + (size_t)l*256*256;
            float acc0 = bo[l*256 + c0], acc1 = bo[l*256 + c1];
            #pragma unroll 8
            for (int k = 0; k < 256; ++k) {
                float a = arow[ty*256 + k];
                float2 wv = *(const float2*)&Wol[(size_t)k*256 + c0];
                acc0 += a*wv.x; acc1 += a*wv.y;
            }

            float2 ndv = *(const float2*)&nodes[(size_t)rg*256 + c0];
            const float* Wgl = Wg + l*3*DIM;
            float sp = acc0*Wgl[c0] + ndv.x*Wgl[DIM+c0] + (acc0-ndv.x)*Wgl[2*DIM+c0]
                     + acc1*Wgl[c1] + ndv.y*Wgl[DIM+c1] + (acc1-ndv.y)*Wgl[2*DIM+c1];
            float tot = rowsum128(sp, red, ty);
            float gate = 1.0f/(1.0f + __expf(-tot));
            float nn0 = acc0*gate + ndv.x*(1.0f - gate);
            float nn1 = acc1*gate + ndv.y*(1.0f - gate);
            *(float2*)&nodes[(size_t)rg*256 + c0] = make_float2(nn0, nn1);

            if (l == 0) {
                float mean = rowsum128(nn0 + nn1, red, ty) * (1.0f/DIM);
                float cc0 = nn0 - mean, cc1 = nn1 - mean;
                float var = rowsum128(cc0*cc0 + cc1*cc1, red, ty) * (1.0f/DIM);
                float rs = 1.0f/sqrtf(var + 1e-5f);
                float h0 = cc0*rs*ln_g[DIM + c0] + ln_b[DIM + c0];
                float h1 = cc1*rs*ln_g[DIM + c1] + ln_b[DIM + c1];
                *(float2*)&hbuf[(size_t)rg*256 + c0] = make_float2(h0, h1);
            } else {
                float s0 = rowsum128(nn0*Wdec[c0*3+0] + nn1*Wdec[c1*3+0], red, ty);
                float s1 = rowsum128(nn0*Wdec[c0*3+1] + nn1*Wdec[c1*3+1], red, ty);
                float s2 = rowsum128(nn0*Wdec[c0*3+2] + nn1*Wdec[c1*3+2], red, ty);
                if (tx == 0) { out[rg*3+0] = s0; out[rg*3+1] = s1; out[rg*3+2] = s2; }
            }
        }
        if (l == 0) gbar(bcnt, bgen);      // hbuf ready for layer-1 QKV
    }
}

extern "C" void kernel_launch(void* const* d_in, const int* in_sizes, int n_in,
                              void* d_out, int out_size, void* d_ws, size_t ws_size,
                              hipStream_t stream) {
    const float* x     = (const float*)d_in[0];
    const float* t     = (const float*)d_in[1];
    const float* W_enc = (const float*)d_in[2];
    const float* W_dec = (const float*)d_in[3];
    const float* ln_g  = (const float*)d_in[4];
    const float* ln_b  = (const float*)d_in[5];
    const float* Wq    = (const float*)d_in[6];
    const float* bq    = (const float*)d_in[7];
    const float* Wkv   = (const float*)d_in[8];
    const float* bkv   = (const float*)d_in[9];
    const float* We    = (const float*)d_in[10];
    const float* be    = (const float*)d_in[11];
    const float* Wo    = (const float*)d_in[12];
    const float* bo    = (const float*)d_in[13];
    const float* Wg    = (const float*)d_in[14];
    float* out = (float*)d_out;

    float* ws = (float*)d_ws;
    float* nodes   = ws;
    float* dist    = nodes   + B*N*DIM;
    float* hbuf    = dist    + B*N*N;
    float* qbuf    = hbuf    + B*N*DIM;
    float* kbuf    = qbuf    + B*N*INNER;
    float* vbuf    = kbuf    + B*N*INNER;
    float* qwe     = vbuf    + B*N*INNER;
    float* qbe     = qwe     + B*HEADS*N;
    float* attnout = qbe     + B*HEADS*N;
    float* ct      = attnout + B*N*INNER;
    float* st      = ct      + N*16;
    unsigned* bar  = (unsigned*)(st + N*16);

    hipMemsetAsync(bar, 0, 2*sizeof(unsigned), stream);
    k_fused<<<NB, 256, 0, stream>>>(x, t, W_enc, W_dec, ln_g, ln_b,
                                    Wq, bq, Wkv, bkv, We, be, Wo, bo, Wg,
                                    nodes, dist, hbuf, qbuf, kbuf, vbuf,
                                    qwe, qbe, attnout, ct, st, out,
                                    bar, bar + 1);
}

// Round 7
// 116.130 us; speedup vs baseline: 6.2016x; 6.2016x over previous
//
#include <hip/hip_runtime.h>
#include <math.h>

#define B 2
#define N 512
#define DIM 256
#define HEADS 8
#define DHEAD 32
#define INNER 256
#define DEPTH 2
#define SCALE 0.17677669529663687f

// ---- block-wide sum over 256 threads (4 waves), result broadcast to all ----
__device__ __forceinline__ float block_sum256(float v, float* red4) {
    #pragma unroll
    for (int o = 32; o; o >>= 1) v += __shfl_xor(v, o);
    int tid = threadIdx.x;
    __syncthreads();                       // protect prior reads of red4
    if ((tid & 63) == 0) red4[tid >> 6] = v;
    __syncthreads();
    return red4[0] + red4[1] + red4[2] + red4[3];
}

// ------- fused: rotary tables (blocks 0..31) + encode + LN0 + dist -------
__global__ void k_pre(const float* __restrict__ x, const float* __restrict__ t,
                      const float* __restrict__ Wenc,
                      const float* __restrict__ ln_g, const float* __restrict__ ln_b,
                      float* __restrict__ nodes, float* __restrict__ hbuf,
                      float* __restrict__ dist,
                      float* __restrict__ ct, float* __restrict__ st) {
    __shared__ float red4[4];
    __shared__ float xs[N * 3];
    int row = blockIdx.x, d = threadIdx.x;
    int b = row >> 9, i = row & (N - 1);

    if (blockIdx.x < 32) {                 // rotary tables: 8192 entries
        int idx = blockIdx.x * 256 + d;
        int ii = idx >> 4, jj = idx & 15;
        double invf = pow(10000.0, -(double)jj / 16.0);
        double ang = (double)ii * invf;
        ct[idx] = (float)cos(ang);
        st[idx] = (float)sin(ang);
    }

    // encode + LN(layer 0)
    float x0 = x[row*3+0], x1 = x[row*3+1], x2 = x[row*3+2], tt = t[row];
    float nv = x0*Wenc[d] + x1*Wenc[DIM+d] + x2*Wenc[2*DIM+d] + tt*Wenc[3*DIM+d];
    nodes[row*DIM + d] = nv;
    float mean = block_sum256(nv, red4) * (1.0f/DIM);
    float c = nv - mean;
    float var = block_sum256(c*c, red4) * (1.0f/DIM);
    hbuf[row*DIM + d] = c * (1.0f/sqrtf(var + 1e-5f)) * ln_g[d] + ln_b[d];

    // dist row i vs all j (x[b] staged in LDS)
    for (int f = d; f < N*3; f += 256) xs[f] = x[b*N*3 + f];
    __syncthreads();
    float xi0 = xs[i*3+0], xi1 = xs[i*3+1], xi2 = xs[i*3+2];
    for (int j = d; j < N; j += 256) {
        float d0 = xi0 - xs[j*3+0], d1 = xi1 - xs[j*3+1], d2 = xi2 - xs[j*3+2];
        float s = d0*d0 + d1*d1 + d2*d2;
        dist[(size_t)row*N + j] = (s > 0.f) ? sqrtf(s) : 0.f;
    }
}

// ------------- QKV GEMM + rotary + qwe/qbe epilogue -------------
__global__ __launch_bounds__(256, 4)
void k_gemm_qkv(const float* __restrict__ hbuf,
                const float* __restrict__ Wq, const float* __restrict__ bq,
                const float* __restrict__ Wkv, const float* __restrict__ bkv,
                const float* __restrict__ We, const float* __restrict__ be,
                const float* __restrict__ ct, const float* __restrict__ st,
                float* __restrict__ qbuf, float* __restrict__ kbuf, float* __restrict__ vbuf,
                float* __restrict__ qwe, float* __restrict__ qbe, int layer) {
    __shared__ float AT[64][32];
    __shared__ float Bs[64][64];

    int tid = threadIdx.x;
    int mt = blockIdx.x & 31;
    int nt = blockIdx.x >> 5;
    int tx = tid & 15, ty = tid >> 4;
    int n0 = nt * 64;

    const float* Wsrc; int wstride;
    if (n0 < 256) { Wsrc = Wq  + (size_t)layer*256*256 + n0;        wstride = 256; }
    else          { Wsrc = Wkv + (size_t)layer*256*512 + (n0-256);  wstride = 512; }

    float acc[2][4] = {{0,0,0,0},{0,0,0,0}};

    int am = tid & 31, ak = tid >> 5;
    int bn4 = tid & 15, bk = tid >> 4;

    for (int kt = 0; kt < 4; ++kt) {
        int kbase = kt * 64;
        if (kt) __syncthreads();
        {
            const float* src = hbuf + (size_t)(mt*32 + am)*256 + kbase + ak*8;
            float4 a0 = *(const float4*)src;
            float4 a1 = *(const float4*)(src + 4);
            AT[ak*8+0][am]=a0.x; AT[ak*8+1][am]=a0.y; AT[ak*8+2][am]=a0.z; AT[ak*8+3][am]=a0.w;
            AT[ak*8+4][am]=a1.x; AT[ak*8+5][am]=a1.y; AT[ak*8+6][am]=a1.z; AT[ak*8+7][am]=a1.w;
        }
        #pragma unroll
        for (int p = 0; p < 4; ++p) {
            int k = bk + p*16;
            float4 v = *(const float4*)(Wsrc + (size_t)(kbase + k)*wstride + bn4*4);
            *(float4*)&Bs[k][bn4*4] = v;
        }
        __syncthreads();
        #pragma unroll 8
        for (int k = 0; k < 64; ++k) {
            float2 a = *(const float2*)&AT[k][ty*2];
            float4 b = *(const float4*)&Bs[k][tx*4];
            acc[0][0] += a.x*b.x; acc[0][1] += a.x*b.y; acc[0][2] += a.x*b.z; acc[0][3] += a.x*b.w;
            acc[1][0] += a.y*b.x; acc[1][1] += a.y*b.y; acc[1][2] += a.y*b.z; acc[1][3] += a.y*b.w;
        }
    }

    int row = mt*32 + ty*2;
    int n = n0 + tx*4;

    float4 bias4;
    if (n0 < 256) bias4 = *(const float4*)&bq[layer*256 + n];
    else          bias4 = *(const float4*)&bkv[layer*512 + (n - 256)];
    #pragma unroll
    for (int r = 0; r < 2; ++r) {
        acc[r][0] += bias4.x; acc[r][1] += bias4.y; acc[r][2] += bias4.z; acc[r][3] += bias4.w;
    }

    if (n0 >= 512) {
        #pragma unroll
        for (int r = 0; r < 2; ++r) {
            float4 o = make_float4(acc[r][0], acc[r][1], acc[r][2], acc[r][3]);
            *(float4*)&vbuf[(size_t)(row + r)*256 + (n - 512)] = o;
        }
        return;
    }

    float* sh = &Bs[0][0];
    __syncthreads();
    #pragma unroll
    for (int r = 0; r < 2; ++r)
        #pragma unroll
        for (int c = 0; c < 4; ++c)
            sh[(ty*2 + r)*68 + tx*4 + c] = acc[r][c];
    __syncthreads();

    float wep[2] = {0.f, 0.f}, bep[2] = {0.f, 0.f};
    float val[2][4];
    #pragma unroll
    for (int r = 0; r < 2; ++r) {
        int ii = (row + r) & (N-1);
        #pragma unroll
        for (int c = 0; c < 4; ++c) {
            int tc = tx*4 + c;
            int dd = tc & 31, jj = tc & 15;
            float ca = ct[ii*16 + jj], sa = st[ii*16 + jj];
            int ptc = (dd < 16) ? tc + 16 : tc - 16;
            float sgn = (dd < 16) ? -1.f : 1.f;
            float partner = sh[(ty*2 + r)*68 + ptc];
            float rot = acc[r][c]*ca + sgn*partner*sa;
            val[r][c] = rot;
            if (n0 < 256) {
                wep[r] += rot * We[layer*256 + n0 + tc];
                bep[r] += rot * be[layer*256 + n0 + tc];
            }
        }
    }

    float* dst = (n0 < 256) ? qbuf : kbuf;
    int coln = (n0 < 256) ? n : n - 256;
    #pragma unroll
    for (int r = 0; r < 2; ++r) {
        float4 o = make_float4(val[r][0], val[r][1], val[r][2], val[r][3]);
        *(float4*)&dst[(size_t)(row + r)*256 + coln] = o;
    }

    if (n0 < 256) {
        #pragma unroll
        for (int r = 0; r < 2; ++r) {
            wep[r] += __shfl_xor(wep[r], 1); bep[r] += __shfl_xor(bep[r], 1);
            wep[r] += __shfl_xor(wep[r], 2); bep[r] += __shfl_xor(bep[r], 2);
            wep[r] += __shfl_xor(wep[r], 4); bep[r] += __shfl_xor(bep[r], 4);
        }
        if ((tid & 7) == 0) {
            int h = nt*2 + (tx >> 3);
            int bb = row >> 9;
            #pragma unroll
            for (int r = 0; r < 2; ++r) {
                int ii = (row + r) & (N-1);
                qwe[(bb*HEADS + h)*N + ii] = wep[r];
                qbe[(bb*HEADS + h)*N + ii] = bep[r];
            }
        }
    }
}

// ------------- attention: TI=16, 2 i-rows per thread -------------
#define TI 16
__global__ __launch_bounds__(256, 2)
void k_attn(const float* __restrict__ qbuf, const float* __restrict__ kbuf,
            const float* __restrict__ vbuf,
            const float* __restrict__ qwe, const float* __restrict__ qbe,
            const float* __restrict__ dist,
            const float* __restrict__ We, const float* __restrict__ be,
            float* __restrict__ attnout, int layer) {
    __shared__ float Tt[32 * 128];

    int t = threadIdx.x;
    int g = t & 31;
    int r = t >> 5;
    int bid = blockIdx.x;
    int itile = bid & 31;
    int h = (bid >> 5) & (HEADS-1);
    int b = bid >> 8;
    int i0 = itile * TI + r;
    int i1 = i0 + 8;

    int scol = t & 127;
    int d0   = (t >> 7) * 16;

    float q0[32], q1[32];
    {
        const float4* qp0 = (const float4*)(qbuf + (size_t)(b*N + i0) * INNER + h * DHEAD);
        const float4* qp1 = (const float4*)(qbuf + (size_t)(b*N + i1) * INNER + h * DHEAD);
        #pragma unroll
        for (int c = 0; c < 8; ++c) {
            float4 v0 = qp0[c], v1 = qp1[c];
            q0[c*4+0] = v0.x; q0[c*4+1] = v0.y; q0[c*4+2] = v0.z; q0[c*4+3] = v0.w;
            q1[c*4+0] = v1.x; q1[c*4+1] = v1.y; q1[c*4+2] = v1.z; q1[c*4+3] = v1.w;
        }
    }
    float qw0 = qwe[(b*HEADS + h)*N + i0], qb0 = qbe[(b*HEADS + h)*N + i0];
    float qw1 = qwe[(b*HEADS + h)*N + i1], qb1 = qbe[(b*HEADS + h)*N + i1];

    const float* kbase = kbuf + (size_t)b*N*INNER + h*DHEAD;
    const float* vbase = vbuf + (size_t)b*N*INNER + h*DHEAD;
    const float* drow0 = dist + (size_t)(b*N + i0) * N;
    const float* drow1 = dist + (size_t)(b*N + i1) * N;

    float sim0[16], sim1[16];

    #pragma unroll
    for (int jt = 0; jt < 4; ++jt) {
        if (jt) __syncthreads();
        {
            const float* src = kbase + (size_t)(jt*128 + scol) * INNER + d0;
            float4 a0 = *(const float4*)(src + 0);
            float4 a1 = *(const float4*)(src + 4);
            float4 a2 = *(const float4*)(src + 8);
            float4 a3 = *(const float4*)(src + 12);
            Tt[(d0+ 0)*128 + scol] = a0.x; Tt[(d0+ 1)*128 + scol] = a0.y;
            Tt[(d0+ 2)*128 + scol] = a0.z; Tt[(d0+ 3)*128 + scol] = a0.w;
            Tt[(d0+ 4)*128 + scol] = a1.x; Tt[(d0+ 5)*128 + scol] = a1.y;
            Tt[(d0+ 6)*128 + scol] = a1.z; Tt[(d0+ 7)*128 + scol] = a1.w;
            Tt[(d0+ 8)*128 + scol] = a2.x; Tt[(d0+ 9)*128 + scol] = a2.y;
            Tt[(d0+10)*128 + scol] = a2.z; Tt[(d0+11)*128 + scol] = a2.w;
            Tt[(d0+12)*128 + scol] = a3.x; Tt[(d0+13)*128 + scol] = a3.y;
            Tt[(d0+14)*128 + scol] = a3.z; Tt[(d0+15)*128 + scol] = a3.w;
        }
        __syncthreads();
        float4 s0 = make_float4(0.f,0.f,0.f,0.f);
        float4 s1 = make_float4(0.f,0.f,0.f,0.f);
        #pragma unroll
        for (int d = 0; d < 32; ++d) {
            float4 kv = *(const float4*)&Tt[d*128 + g*4];
            float qa = q0[d], qc = q1[d];
            s0.x += qa*kv.x; s0.y += qa*kv.y; s0.z += qa*kv.z; s0.w += qa*kv.w;
            s1.x += qc*kv.x; s1.y += qc*kv.y; s1.z += qc*kv.z; s1.w += qc*kv.w;
        }
        float4 dv0 = *(const float4*)&drow0[jt*128 + g*4];
        float4 dv1 = *(const float4*)&drow1[jt*128 + g*4];
        sim0[jt*4+0] = (s0.x + dv0.x*qw0 + qb0) * SCALE;
        sim0[jt*4+1] = (s0.y + dv0.y*qw0 + qb0) * SCALE;
        sim0[jt*4+2] = (s0.z + dv0.z*qw0 + qb0) * SCALE;
        sim0[jt*4+3] = (s0.w + dv0.w*qw0 + qb0) * SCALE;
        sim1[jt*4+0] = (s1.x + dv1.x*qw1 + qb1) * SCALE;
        sim1[jt*4+1] = (s1.y + dv1.y*qw1 + qb1) * SCALE;
        sim1[jt*4+2] = (s1.z + dv1.z*qw1 + qb1) * SCALE;
        sim1[jt*4+3] = (s1.w + dv1.w*qw1 + qb1) * SCALE;
    }

    float mx0 = -1e30f, mx1 = -1e30f;
    #pragma unroll
    for (int v = 0; v < 16; ++v) { mx0 = fmaxf(mx0, sim0[v]); mx1 = fmaxf(mx1, sim1[v]); }
    #pragma unroll
    for (int o = 1; o <= 16; o <<= 1) {
        mx0 = fmaxf(mx0, __shfl_xor(mx0, o));
        mx1 = fmaxf(mx1, __shfl_xor(mx1, o));
    }

    float ls0 = 0.f, ld0 = 0.f, ls1 = 0.f, ld1 = 0.f;
    #pragma unroll
    for (int jt = 0; jt < 4; ++jt) {
        float4 dv0 = *(const float4*)&drow0[jt*128 + g*4];
        float4 dv1 = *(const float4*)&drow1[jt*128 + g*4];
        float a0[4] = {dv0.x,dv0.y,dv0.z,dv0.w};
        float a1[4] = {dv1.x,dv1.y,dv1.z,dv1.w};
        #pragma unroll
        for (int u = 0; u < 4; ++u) {
            float p0 = __expf(sim0[jt*4+u] - mx0);
            float p1 = __expf(sim1[jt*4+u] - mx1);
            sim0[jt*4+u] = p0; sim1[jt*4+u] = p1;
            ls0 += p0; ld0 += p0 * a0[u];
            ls1 += p1; ld1 += p1 * a1[u];
        }
    }
    #pragma unroll
    for (int o = 1; o <= 16; o <<= 1) {
        ls0 += __shfl_xor(ls0, o); ld0 += __shfl_xor(ld0, o);
        ls1 += __shfl_xor(ls1, o); ld1 += __shfl_xor(ld1, o);
    }

    float acc0[32], acc1[32];
    #pragma unroll
    for (int d = 0; d < 32; ++d) { acc0[d] = 0.f; acc1[d] = 0.f; }

    #pragma unroll
    for (int jt = 0; jt < 4; ++jt) {
        __syncthreads();
        {
            const float* src = vbase + (size_t)(jt*128 + scol) * INNER + d0;
            float4 a0 = *(const float4*)(src + 0);
            float4 a1 = *(const float4*)(src + 4);
            float4 a2 = *(const float4*)(src + 8);
            float4 a3 = *(const float4*)(src + 12);
            Tt[(d0+ 0)*128 + scol] = a0.x; Tt[(d0+ 1)*128 + scol] = a0.y;
            Tt[(d0+ 2)*128 + scol] = a0.z; Tt[(d0+ 3)*128 + scol] = a0.w;
            Tt[(d0+ 4)*128 + scol] = a1.x; Tt[(d0+ 5)*128 + scol] = a1.y;
            Tt[(d0+ 6)*128 + scol] = a1.z; Tt[(d0+ 7)*128 + scol] = a1.w;
            Tt[(d0+ 8)*128 + scol] = a2.x; Tt[(d0+ 9)*128 + scol] = a2.y;
            Tt[(d0+10)*128 + scol] = a2.z; Tt[(d0+11)*128 + scol] = a2.w;
            Tt[(d0+12)*128 + scol] = a3.x; Tt[(d0+13)*128 + scol] = a3.y;
            Tt[(d0+14)*128 + scol] = a3.z; Tt[(d0+15)*128 + scol] = a3.w;
        }
        __syncthreads();
        float p00 = sim0[jt*4+0], p01 = sim0[jt*4+1], p02 = sim0[jt*4+2], p03 = sim0[jt*4+3];
        float p10 = sim1[jt*4+0], p11 = sim1[jt*4+1], p12 = sim1[jt*4+2], p13 = sim1[jt*4+3];
        #pragma unroll
        for (int d = 0; d < 32; ++d) {
            float4 vv = *(const float4*)&Tt[d*128 + g*4];
            acc0[d] += p00*vv.x + p01*vv.y + p02*vv.z + p03*vv.w;
            acc1[d] += p10*vv.x + p11*vv.y + p12*vv.z + p13*vv.w;
        }
    }

    #pragma unroll
    for (int d = 0; d < 32; ++d) {
        #pragma unroll
        for (int o = 1; o <= 16; o <<= 1) {
            acc0[d] += __shfl_xor(acc0[d], o);
            acc1[d] += __shfl_xor(acc1[d], o);
        }
    }

    float il0 = 1.0f / ls0, il1 = 1.0f / ls1;
    float ad0 = ld0 * il0, ad1 = ld1 * il1;
    float o0 = acc0[0], o1 = acc1[0];
    #pragma unroll
    for (int d = 1; d < 32; ++d) if (g == d) { o0 = acc0[d]; o1 = acc1[d]; }
    float wv = We[layer*INNER + h*DHEAD + g];
    float bv = be[layer*INNER + h*DHEAD + g];
    attnout[(size_t)(b*N + i0)*INNER + h*DHEAD + g] = o0*il0 + ad0*wv + bv;
    attnout[(size_t)(b*N + i1)*INNER + h*DHEAD + g] = o1*il1 + ad1*wv + bv;
}

// ---- fused O-GEMM + gate + LN(next)/decode: wave-per-row, 4 rows/block ----
__global__ __launch_bounds__(256, 4)
void k_ogate(const float* __restrict__ attnout,
             const float* __restrict__ Wo, const float* __restrict__ bo,
             const float* __restrict__ Wg,
             const float* __restrict__ ln_g, const float* __restrict__ ln_b,
             const float* __restrict__ Wdec,
             float* __restrict__ nodes, float* __restrict__ hbuf,
             float* __restrict__ out, int layer) {
    __shared__ float arow[4*256];          // 4 attnout rows
    int tid = threadIdx.x;
    int w = tid >> 6;                      // wave = row within block
    int lane = tid & 63;
    int rg = blockIdx.x*4 + w;             // global row
    int c0 = lane*4;

    *(float4*)&arow[tid*4] = *(const float4*)&attnout[(size_t)blockIdx.x*1024 + tid*4];
    __syncthreads();

    const float* Wol = Wo + (size_t)layer*256*256;
    float4 bias = *(const float4*)&bo[layer*256 + c0];
    float a0 = bias.x, a1 = bias.y, a2 = bias.z, a3 = bias.w;
    const float* ar = &arow[w*256];
    #pragma unroll 8
    for (int k = 0; k < 256; ++k) {
        float a = ar[k];
        float4 wv = *(const float4*)&Wol[(size_t)k*256 + c0];
        a0 += a*wv.x; a1 += a*wv.y; a2 += a*wv.z; a3 += a*wv.w;
    }

    float4 nd = *(const float4*)&nodes[(size_t)rg*256 + c0];
    const float* Wgl = Wg + layer*3*DIM;
    float4 g1 = *(const float4*)&Wgl[c0];
    float4 g2 = *(const float4*)&Wgl[DIM + c0];
    float4 g3 = *(const float4*)&Wgl[2*DIM + c0];
    float sp = a0*g1.x + nd.x*g2.x + (a0-nd.x)*g3.x
             + a1*g1.y + nd.y*g2.y + (a1-nd.y)*g3.y
             + a2*g1.z + nd.z*g2.z + (a2-nd.z)*g3.z
             + a3*g1.w + nd.w*g2.w + (a3-nd.w)*g3.w;
    #pragma unroll
    for (int o = 32; o; o >>= 1) sp += __shfl_xor(sp, o);
    float gate = 1.0f/(1.0f + __expf(-sp));
    float n0 = a0*gate + nd.x*(1.0f-gate);
    float n1 = a1*gate + nd.y*(1.0f-gate);
    float n2 = a2*gate + nd.z*(1.0f-gate);
    float n3 = a3*gate + nd.w*(1.0f-gate);
    *(float4*)&nodes[(size_t)rg*256 + c0] = make_float4(n0, n1, n2, n3);

    if (layer == 0) {
        float ms = n0 + n1 + n2 + n3;
        #pragma unroll
        for (int o = 32; o; o >>= 1) ms += __shfl_xor(ms, o);
        float mean = ms * (1.0f/DIM);
        float c0v = n0-mean, c1v = n1-mean, c2v = n2-mean, c3v = n3-mean;
        float vs = c0v*c0v + c1v*c1v + c2v*c2v + c3v*c3v;
        #pragma unroll
        for (int o = 32; o; o >>= 1) vs += __shfl_xor(vs, o);
        float rs = 1.0f/sqrtf(vs*(1.0f/DIM) + 1e-5f);
        float4 lg = *(const float4*)&ln_g[DIM + c0];
        float4 lb = *(const float4*)&ln_b[DIM + c0];
        float4 h = make_float4(c0v*rs*lg.x + lb.x, c1v*rs*lg.y + lb.y,
                               c2v*rs*lg.z + lb.z, c3v*rs*lg.w + lb.w);
        *(float4*)&hbuf[(size_t)rg*256 + c0] = h;
    } else {
        float s0 = n0*Wdec[(c0+0)*3+0] + n1*Wdec[(c0+1)*3+0] + n2*Wdec[(c0+2)*3+0] + n3*Wdec[(c0+3)*3+0];
        float s1 = n0*Wdec[(c0+0)*3+1] + n1*Wdec[(c0+1)*3+1] + n2*Wdec[(c0+2)*3+1] + n3*Wdec[(c0+3)*3+1];
        float s2 = n0*Wdec[(c0+0)*3+2] + n1*Wdec[(c0+1)*3+2] + n2*Wdec[(c0+2)*3+2] + n3*Wdec[(c0+3)*3+2];
        #pragma unroll
        for (int o = 32; o; o >>= 1) {
            s0 += __shfl_xor(s0, o); s1 += __shfl_xor(s1, o); s2 += __shfl_xor(s2, o);
        }
        if (lane == 0) { out[rg*3+0] = s0; out[rg*3+1] = s1; out[rg*3+2] = s2; }
    }
}

extern "C" void kernel_launch(void* const* d_in, const int* in_sizes, int n_in,
                              void* d_out, int out_size, void* d_ws, size_t ws_size,
                              hipStream_t stream) {
    const float* x     = (const float*)d_in[0];
    const float* t     = (const float*)d_in[1];
    const float* W_enc = (const float*)d_in[2];
    const float* W_dec = (const float*)d_in[3];
    const float* ln_g  = (const float*)d_in[4];
    const float* ln_b  = (const float*)d_in[5];
    const float* Wq    = (const float*)d_in[6];
    const float* bq    = (const float*)d_in[7];
    const float* Wkv   = (const float*)d_in[8];
    const float* bkv   = (const float*)d_in[9];
    const float* We    = (const float*)d_in[10];
    const float* be    = (const float*)d_in[11];
    const float* Wo    = (const float*)d_in[12];
    const float* bo    = (const float*)d_in[13];
    const float* Wg    = (const float*)d_in[14];
    float* out = (float*)d_out;

    float* ws = (float*)d_ws;
    float* nodes   = ws;
    float* dist    = nodes   + B*N*DIM;
    float* hbuf    = dist    + B*N*N;
    float* qbuf    = hbuf    + B*N*DIM;
    float* kbuf    = qbuf    + B*N*INNER;
    float* vbuf    = kbuf    + B*N*INNER;
    float* qwe     = vbuf    + B*N*INNER;
    float* qbe     = qwe     + B*HEADS*N;
    float* attnout = qbe     + B*HEADS*N;
    float* ct      = attnout + B*N*INNER;
    float* st      = ct      + N*16;

    k_pre<<<B*N, DIM, 0, stream>>>(x, t, W_enc, ln_g, ln_b, nodes, hbuf, dist, ct, st);
    for (int l = 0; l < DEPTH; ++l) {
        k_gemm_qkv<<<384, 256, 0, stream>>>(hbuf, Wq, bq, Wkv, bkv, We, be, ct, st,
                                            qbuf, kbuf, vbuf, qwe, qbe, l);
        k_attn<<<B*HEADS*(N/TI), 256, 0, stream>>>(qbuf, kbuf, vbuf, qwe, qbe, dist, We, be,
                                                   attnout, l);
        k_ogate<<<B*N/4, 256, 0, stream>>>(attnout, Wo, bo, Wg, ln_g, ln_b, W_dec,
                                           nodes, hbuf, out, l);
    }
}